// Round 11
// baseline (366.078 us; speedup 1.0000x reference)
//
#include <hip/hip_runtime.h>
#include <hip/hip_bf16.h>

typedef __hip_bfloat16 bf16;
typedef __attribute__((ext_vector_type(8))) short short8;
typedef __attribute__((ext_vector_type(4))) float f32x4;

#define DDIM 1024
#define SEQ  4096
#define NB   4
#define MTOT (NB*SEQ)   // 16384 rows

static __device__ __forceinline__ unsigned short f2bf(float f) {
    __hip_bfloat16 h = __float2bfloat16(f);
    unsigned short u; __builtin_memcpy(&u, &h, 2); return u;
}
static __device__ __forceinline__ float bf2f(unsigned short u) {
    __hip_bfloat16 h; __builtin_memcpy(&h, &u, 2); return __bfloat162float(h);
}

// ---------------------------------------- fused: cast weights (blocks 0..1023)
//                                          + colsum partial    (blocks 1024..1535)
//                                          + zero gemm2 completion counters
__global__ __launch_bounds__(256) void prep_kernel(
    const float* __restrict__ w1, const float* __restrict__ w2,
    unsigned short* __restrict__ w1b, unsigned short* __restrict__ w2b,
    const float* __restrict__ x, float* __restrict__ partial,
    int* __restrict__ cnt)
{
    int bid = blockIdx.x;
    if (bid == 0 && threadIdx.x < 128) cnt[threadIdx.x] = 0;   // re-zeroed every call
    if (bid < 1024) {
        size_t idx = ((size_t)bid*256 + threadIdx.x) * 4;
        float4 a = *(const float4*)(w1 + idx);
        ushort4 o; o.x=f2bf(a.x); o.y=f2bf(a.y); o.z=f2bf(a.z); o.w=f2bf(a.w);
        *(ushort4*)(w1b + idx) = o;
        float4 b = *(const float4*)(w2 + idx);
        o.x=f2bf(b.x); o.y=f2bf(b.y); o.z=f2bf(b.z); o.w=f2bf(b.w);
        *(ushort4*)(w2b + idx) = o;
    } else {
        int idx = bid - 1024;               // [0,512): dx 0..3, b 0..3, sl 0..31
        int dx = idx & 3, b = (idx >> 2) & 3, sl = idx >> 4;
        int d  = dx*256 + threadIdx.x;
        const float* p = x + ((size_t)b*SEQ + (size_t)sl*128)*DDIM + d;
        float s = 0.f;
        #pragma unroll 4
        for (int i = 0; i < 128; ++i) s += p[(size_t)i*DDIM];
        partial[((size_t)sl*NB + b)*DDIM + d] = s;
    }
}

// ------------------------------- matvec1: fused colsum-reduce + tvec = xsum @ Wv^T
__global__ __launch_bounds__(256) void matvec1_kernel(
    const float* __restrict__ W, const float* __restrict__ partial,
    float* __restrict__ vout)
{
    int b = blockIdx.y;
    __shared__ float vloc[DDIM];
    #pragma unroll
    for (int j = 0; j < 4; ++j) {                     // redundant per-block reduce (L2-hot)
        int d = j*256 + threadIdx.x;
        float s = 0.f;
        #pragma unroll
        for (int sl = 0; sl < 32; ++sl) s += partial[((size_t)sl*NB + b)*DDIM + d];
        vloc[d] = s;
    }
    __syncthreads();
    int g = threadIdx.x >> 4;
    int t = threadIdx.x & 15;
    int e = blockIdx.x*16 + g;
    const float* w = W + (size_t)e*DDIM;
    float s = 0.f;
    for (int k = t; k < DDIM; k += 16) s += w[k]*vloc[k];
    #pragma unroll
    for (int o = 8; o; o >>= 1) s += __shfl_down(s, o, 16);
    if (t == 0) vout[b*DDIM + e] = s;
}

// ------------------------------------------------------- small matvec: vout = vin @ W^T
__global__ __launch_bounds__(256) void matvec_kernel(
    const float* __restrict__ W, const float* __restrict__ vin, float* __restrict__ vout)
{
    int b = blockIdx.y;
    int g = threadIdx.x >> 4;
    int t = threadIdx.x & 15;
    int e = blockIdx.x*16 + g;
    const float* w = W + (size_t)e*DDIM;
    const float* v = vin + b*DDIM;
    float s = 0.f;
    for (int k = t; k < DDIM; k += 16) s += w[k]*v[k];
    #pragma unroll
    for (int o = 8; o; o >>= 1) s += __shfl_down(s, o, 16);
    if (t == 0) vout[b*DDIM + e] = s;
}

// ------------------------------------------------------- LN1: x1 = LN(x + attnvec) -> bf16
__global__ __launch_bounds__(256) void ln1_kernel(
    const float* __restrict__ x, const float* __restrict__ avec,
    const float* __restrict__ g1, const float* __restrict__ b1,
    unsigned short* __restrict__ x1b)
{
    int row = blockIdx.x;
    int b   = row >> 12;          // row / SEQ
    int tid = threadIdx.x;
    const float4* xr = (const float4*)(x + (size_t)row*DDIM);
    const float4* av = (const float4*)(avec + (size_t)b*DDIM);
    float4 xv = xr[tid], a4 = av[tid];
    float y0 = xv.x+a4.x, y1 = xv.y+a4.y, y2 = xv.z+a4.z, y3 = xv.w+a4.w;
    float s  = y0+y1+y2+y3;
    float ss = y0*y0+y1*y1+y2*y2+y3*y3;
    #pragma unroll
    for (int o = 32; o; o >>= 1) { s += __shfl_down(s,o,64); ss += __shfl_down(ss,o,64); }
    __shared__ float red[8];
    if ((tid&63) == 0) { red[tid>>6] = s; red[4+(tid>>6)] = ss; }
    __syncthreads();
    float St = red[0]+red[1]+red[2]+red[3];
    float Sq = red[4]+red[5]+red[6]+red[7];
    float mu = St*(1.0f/DDIM);
    float rs = rsqrtf(Sq*(1.0f/DDIM) - mu*mu + 1e-5f);
    float4 g4 = ((const float4*)g1)[tid];
    float4 bb = ((const float4*)b1)[tid];
    ushort4 o;
    o.x = f2bf((y0-mu)*rs*g4.x + bb.x);
    o.y = f2bf((y1-mu)*rs*g4.y + bb.y);
    o.z = f2bf((y2-mu)*rs*g4.z + bb.z);
    o.w = f2bf((y3-mu)*rs*g4.w + bb.w);
    *(ushort4*)(x1b + (size_t)row*DDIM + tid*4) = o;
}

// ------------------------------------------------------- GEMM1: round-3 proven config
// 128x128 tile, BK=64, double-buffered 64 KB LDS, counted vmcnt(8), 2 blocks/CU.
// outb = bf16(gelu(A@W1^T + b1))
__global__ __launch_bounds__(256, 2) void gemm1_kernel(
    const bf16* __restrict__ A, const bf16* __restrict__ Bw,
    const float* __restrict__ bias, unsigned short* __restrict__ outb)
{
    constexpr int K = 1024, N = 1024, BK = 64, NT = K / BK;   // 16 K-tiles
    __shared__ __align__(16) bf16 lds[2][2][128*BK];          // 64 KB
    const int tid  = threadIdx.x;
    const int wave = tid >> 6, lane = tid & 63;

    int bid = blockIdx.x;
    int swz = (bid & 7) * 128 + (bid >> 3);     // T1 bijective XCD swizzle (grid 1024)
    const size_t bm = (size_t)(swz >> 3) * 128;
    const size_t bn = (size_t)(swz & 7) * 128;

    const int wm = wave >> 1;     // 0..1
    const int wn = wave & 1;      // 0..1

    const int srow = tid >> 3;
    const int skel = (((tid & 7) ^ ((tid >> 3) & 7)) << 3);

    const int fr = lane & 15;
    const int fs = lane >> 4;
    int foff[2];
    #pragma unroll
    for (int ks = 0; ks < 2; ++ks)
        foff[ks] = fr*128 + (((ks*4 + fs) ^ (fr & 7)) << 4);

    f32x4 acc[4][4] = {};
    const bf16* Ab = A  + bm * K;
    const bf16* Bb = Bw + bn * K;

    auto stage = [&](int b, int kt) {        // 8 global_load_lds (16B each)
        #pragma unroll
        for (int mat = 0; mat < 2; ++mat) {
            const bf16* src = (mat == 0 ? Ab : Bb);
            #pragma unroll
            for (int g = 0; g < 4; ++g) {
                int row = g*32 + srow;
                const bf16* gp = src + (size_t)row * K + kt*BK + skel;
                __builtin_amdgcn_global_load_lds(
                    (const __attribute__((address_space(1))) void*)gp,
                    (__attribute__((address_space(3))) void*)
                        ((char*)&lds[b][mat][0] + g*4096 + wave*1024),
                    16, 0, 0);
            }
        }
    };

    stage(0, 0);

    #pragma unroll 2
    for (int t = 0; t < NT; ++t) {
        const int cur = t & 1;
        if (t < NT-1) {
            stage(cur ^ 1, t + 1);
            asm volatile("s_waitcnt vmcnt(8)" ::: "memory");
        } else {
            asm volatile("s_waitcnt vmcnt(0)" ::: "memory");
        }
        __builtin_amdgcn_s_barrier();

        const char* LA = (const char*)&lds[cur][0][0] + wm*8192;
        const char* LB = (const char*)&lds[cur][1][0] + wn*8192;
        #pragma unroll
        for (int ks = 0; ks < 2; ++ks) {
            short8 af[4], bfr[4];
            #pragma unroll
            for (int m = 0; m < 4; ++m) af[m]  = *(const short8*)(LA + m*2048 + foff[ks]);
            #pragma unroll
            for (int n = 0; n < 4; ++n) bfr[n] = *(const short8*)(LB + n*2048 + foff[ks]);
            __builtin_amdgcn_s_setprio(1);
            #pragma unroll
            for (int m = 0; m < 4; ++m)
                #pragma unroll
                for (int n = 0; n < 4; ++n)
                    acc[m][n] = __builtin_amdgcn_mfma_f32_16x16x32_bf16(
                        af[m], bfr[n], acc[m][n], 0, 0, 0);
            __builtin_amdgcn_s_setprio(0);
        }
        __builtin_amdgcn_s_barrier();
    }

    #pragma unroll
    for (int n = 0; n < 4; ++n) {
        size_t col = bn + wn*64 + n*16 + fr;
        float bv = bias[col];
        #pragma unroll
        for (int m = 0; m < 4; ++m) {
            #pragma unroll
            for (int r = 0; r < 4; ++r) {
                size_t row = bm + wm*64 + m*16 + fs*4 + r;
                float v = acc[m][n][r] + bv;
                float ge = 0.5f*v*(1.0f + erff(v*0.70710678118f));
                outb[row*(size_t)N + col] = f2bf(ge);
            }
        }
    }
}

// ------------------------------------------------------- GEMM2 + fused LN2 (last-block apply)
// y = bf16(A@W2^T + b2 + resid) in place over resid (xy); per-block row stats -> part;
// last block of each 128-row group (via device-scope counter) applies LN2 -> out fp32.
__global__ __launch_bounds__(256, 2) void gemm2_kernel(
    const bf16* __restrict__ A, const bf16* __restrict__ Bw,
    const float* __restrict__ bias, unsigned short* __restrict__ xy,
    float2* __restrict__ part, int* __restrict__ cnt,
    const float* __restrict__ g2, const float* __restrict__ b2,
    float* __restrict__ out)
{
    constexpr int K = 1024, N = 1024, BK = 64, NT = K / BK;   // 16 K-tiles
    __shared__ __align__(16) bf16 lds[2][2][128*BK];          // 64 KB
    const int tid  = threadIdx.x;
    const int wave = tid >> 6, lane = tid & 63;

    int bid = blockIdx.x;
    int swz = (bid & 7) * 128 + (bid >> 3);
    const size_t bm = (size_t)(swz >> 3) * 128;
    const size_t bn = (size_t)(swz & 7) * 128;

    const int wm = wave >> 1;
    const int wn = wave & 1;

    const int srow = tid >> 3;
    const int skel = (((tid & 7) ^ ((tid >> 3) & 7)) << 3);

    const int fr = lane & 15;
    const int fs = lane >> 4;
    int foff[2];
    #pragma unroll
    for (int ks = 0; ks < 2; ++ks)
        foff[ks] = fr*128 + (((ks*4 + fs) ^ (fr & 7)) << 4);

    f32x4 acc[4][4] = {};
    const bf16* Ab = A  + bm * K;
    const bf16* Bb = Bw + bn * K;

    auto stage = [&](int b, int kt) {
        #pragma unroll
        for (int mat = 0; mat < 2; ++mat) {
            const bf16* src = (mat == 0 ? Ab : Bb);
            #pragma unroll
            for (int g = 0; g < 4; ++g) {
                int row = g*32 + srow;
                const bf16* gp = src + (size_t)row * K + kt*BK + skel;
                __builtin_amdgcn_global_load_lds(
                    (const __attribute__((address_space(1))) void*)gp,
                    (__attribute__((address_space(3))) void*)
                        ((char*)&lds[b][mat][0] + g*4096 + wave*1024),
                    16, 0, 0);
            }
        }
    };

    stage(0, 0);

    #pragma unroll 2
    for (int t = 0; t < NT; ++t) {
        const int cur = t & 1;
        if (t < NT-1) {
            stage(cur ^ 1, t + 1);
            asm volatile("s_waitcnt vmcnt(8)" ::: "memory");
        } else {
            asm volatile("s_waitcnt vmcnt(0)" ::: "memory");
        }
        __builtin_amdgcn_s_barrier();

        const char* LA = (const char*)&lds[cur][0][0] + wm*8192;
        const char* LB = (const char*)&lds[cur][1][0] + wn*8192;
        #pragma unroll
        for (int ks = 0; ks < 2; ++ks) {
            short8 af[4], bfr[4];
            #pragma unroll
            for (int m = 0; m < 4; ++m) af[m]  = *(const short8*)(LA + m*2048 + foff[ks]);
            #pragma unroll
            for (int n = 0; n < 4; ++n) bfr[n] = *(const short8*)(LB + n*2048 + foff[ks]);
            __builtin_amdgcn_s_setprio(1);
            #pragma unroll
            for (int m = 0; m < 4; ++m)
                #pragma unroll
                for (int n = 0; n < 4; ++n)
                    acc[m][n] = __builtin_amdgcn_mfma_f32_16x16x32_bf16(
                        af[m], bfr[n], acc[m][n], 0, 0, 0);
            __builtin_amdgcn_s_setprio(0);
        }
        __builtin_amdgcn_s_barrier();
    }

    // ---- epilogue: quantize y to bf16 in place, accumulate row stats of quantized y
    float vs[4][4] = {}, vq[4][4] = {};
    #pragma unroll
    for (int n = 0; n < 4; ++n) {
        size_t col = bn + wn*64 + n*16 + fr;
        float bv = bias[col];
        #pragma unroll
        for (int m = 0; m < 4; ++m) {
            #pragma unroll
            for (int r = 0; r < 4; ++r) {
                size_t row = bm + wm*64 + m*16 + fs*4 + r;
                size_t idx = row*(size_t)N + col;
                float v = acc[m][n][r] + bv + bf2f(xy[idx]);
                unsigned short qb = f2bf(v);
                xy[idx] = qb;                      // y bf16, in place over resid
                float vv = bf2f(qb);
                vs[m][r] += vv;
                vq[m][r] += vv*vv;
            }
        }
    }
    #pragma unroll
    for (int o = 1; o < 16; o <<= 1) {
        #pragma unroll
        for (int m = 0; m < 4; ++m)
            #pragma unroll
            for (int r = 0; r < 4; ++r) {
                vs[m][r] += __shfl_xor(vs[m][r], o);
                vq[m][r] += __shfl_xor(vq[m][r], o);
            }
    }
    float* lred = (float*)&lds[0][0][0];           // [wn:2][128 rows][2]
    if (fr == 0) {
        #pragma unroll
        for (int m = 0; m < 4; ++m)
            #pragma unroll
            for (int r = 0; r < 4; ++r) {
                int rl = wm*64 + m*16 + fs*4 + r;
                lred[(wn*128 + rl)*2]     = vs[m][r];
                lred[(wn*128 + rl)*2 + 1] = vq[m][r];
            }
    }
    __syncthreads();
    if (tid < 128) {
        float s  = lred[tid*2]       + lred[(128 + tid)*2];
        float sq = lred[tid*2 + 1]   + lred[(128 + tid)*2 + 1];
        part[(bm + tid)*8 + (bn >> 7)] = make_float2(s, sq);
    }

    // ---- completion counter: last block of this 128-row group applies LN2
    __threadfence();                               // release xy + part writes (device scope)
    __shared__ int lastFlag;
    if (tid == 0) {
        int prev = atomicAdd(cnt + (int)(bm >> 7), 1);
        lastFlag = (prev == 7);                    // 8 column-blocks per row group
    }
    __syncthreads();
    if (lastFlag) {
        __threadfence();                           // acquire other blocks' xy/part
        float4 g4 = ((const float4*)g2)[tid];
        float4 bb = ((const float4*)b2)[tid];
        for (int r = 0; r < 128; ++r) {
            size_t row = bm + r;
            float s = 0.f, sq = 0.f;
            #pragma unroll
            for (int i = 0; i < 8; ++i) {          // uniform addr -> broadcast loads
                float2 p = part[row*8 + i];
                s += p.x; sq += p.y;
            }
            float mu = s * (1.0f/DDIM);
            float rs = rsqrtf(sq * (1.0f/DDIM) - mu*mu + 1e-5f);
            ushort4 yv = *(const ushort4*)(xy + row*DDIM + tid*4);
            float4 o;
            o.x = (bf2f(yv.x) - mu)*rs*g4.x + bb.x;
            o.y = (bf2f(yv.y) - mu)*rs*g4.y + bb.y;
            o.z = (bf2f(yv.z) - mu)*rs*g4.z + bb.z;
            o.w = (bf2f(yv.w) - mu)*rs*g4.w + bb.w;
            ((float4*)(out + row*DDIM))[tid] = o;
        }
    }
}

// ---------------------------------------------------------------- launch
extern "C" void kernel_launch(void* const* d_in, const int* in_sizes, int n_in,
                              void* d_out, int out_size, void* d_ws, size_t ws_size,
                              hipStream_t stream)
{
    const float* x     = (const float*)d_in[0];
    const float* w_qkv = (const float*)d_in[1];
    const float* w_o   = (const float*)d_in[2];
    const float* w1    = (const float*)d_in[3];
    const float* b1    = (const float*)d_in[4];
    const float* w2    = (const float*)d_in[5];
    const float* b2    = (const float*)d_in[6];
    const float* ln1g  = (const float*)d_in[7];
    const float* ln1b  = (const float*)d_in[8];
    const float* ln2g  = (const float*)d_in[9];
    const float* ln2b  = (const float*)d_in[10];
    float* out = (float*)d_out;
    char* ws = (char*)d_ws;

    unsigned short* x1b = (unsigned short*)(ws);               // 32 MB  x1 bf16 -> later y bf16
    unsigned short* hb  = (unsigned short*)(ws + 33554432);    // 32 MB  h  bf16
    unsigned short* w1b = (unsigned short*)(ws + 67108864);    // 2 MB   (dead after GEMM1 -> partials)
    unsigned short* w2b = (unsigned short*)(ws + 69206016);    // 2 MB
    float* partial = (float*)(ws + 71303168);                  // 512 KB (colsum)
    float* tvec    = (float*)(ws + 71843840);                  // 16 KB
    float* avec    = (float*)(ws + 71860224);                  // 16 KB
    int*   cnt     = (int*)(ws + 71876608);                    // 512 B completion counters
    float2* lnpart = (float2*)(ws + 67108864);                 // 1 MB, aliases w1b (safe: GEMM1 done)

    prep_kernel<<<dim3(1536), 256, 0, stream>>>(w1, w2, w1b, w2b, x, partial, cnt);
    matvec1_kernel<<<dim3(64, NB), 256, 0, stream>>>(
        w_qkv + (size_t)2*DDIM*DDIM, partial, tvec);
    matvec_kernel<<<dim3(64, NB), 256, 0, stream>>>(w_o, tvec, avec);
    ln1_kernel<<<dim3(MTOT), 256, 0, stream>>>(x, avec, ln1g, ln1b, x1b);
    gemm1_kernel<<<dim3(1024), 256, 0, stream>>>(
        (const bf16*)x1b, (const bf16*)w1b, b1, hb);
    gemm2_kernel<<<dim3(1024), 256, 0, stream>>>(
        (const bf16*)hb, (const bf16*)w2b, b2, x1b, lnpart, cnt, ln2g, ln2b, out);
}

// Round 12
// 163.355 us; speedup vs baseline: 2.2410x; 2.2410x over previous
//
#include <hip/hip_runtime.h>
#include <hip/hip_bf16.h>

typedef __hip_bfloat16 bf16;
typedef __attribute__((ext_vector_type(8))) short short8;
typedef __attribute__((ext_vector_type(4))) float f32x4;

#define DDIM 1024
#define SEQ  4096
#define NB   4
#define MTOT (NB*SEQ)   // 16384 rows

static __device__ __forceinline__ unsigned short f2bf(float f) {
    __hip_bfloat16 h = __float2bfloat16(f);
    unsigned short u; __builtin_memcpy(&u, &h, 2); return u;
}
static __device__ __forceinline__ float bf2f(unsigned short u) {
    __hip_bfloat16 h; __builtin_memcpy(&h, &u, 2); return __bfloat162float(h);
}

// ---------------------------------------- fused: cast weights (blocks 0..1023)
//                                          + colsum partial    (blocks 1024..1535)
__global__ __launch_bounds__(256) void prep_kernel(
    const float* __restrict__ w1, const float* __restrict__ w2,
    unsigned short* __restrict__ w1b, unsigned short* __restrict__ w2b,
    const float* __restrict__ x, float* __restrict__ partial)
{
    int bid = blockIdx.x;
    if (bid < 1024) {
        size_t idx = ((size_t)bid*256 + threadIdx.x) * 4;
        float4 a = *(const float4*)(w1 + idx);
        ushort4 o; o.x=f2bf(a.x); o.y=f2bf(a.y); o.z=f2bf(a.z); o.w=f2bf(a.w);
        *(ushort4*)(w1b + idx) = o;
        float4 b = *(const float4*)(w2 + idx);
        o.x=f2bf(b.x); o.y=f2bf(b.y); o.z=f2bf(b.z); o.w=f2bf(b.w);
        *(ushort4*)(w2b + idx) = o;
    } else {
        int idx = bid - 1024;               // [0,512): dx 0..3, b 0..3, sl 0..31
        int dx = idx & 3, b = (idx >> 2) & 3, sl = idx >> 4;
        int d  = dx*256 + threadIdx.x;
        const float* p = x + ((size_t)b*SEQ + (size_t)sl*128)*DDIM + d;
        float s = 0.f;
        #pragma unroll 4
        for (int i = 0; i < 128; ++i) s += p[(size_t)i*DDIM];
        partial[((size_t)sl*NB + b)*DDIM + d] = s;
    }
}

// ------------------------------- matvec1: fused colsum-reduce + tvec = xsum @ Wv^T
__global__ __launch_bounds__(256) void matvec1_kernel(
    const float* __restrict__ W, const float* __restrict__ partial,
    float* __restrict__ vout)
{
    int b = blockIdx.y;
    __shared__ float vloc[DDIM];
    #pragma unroll
    for (int j = 0; j < 4; ++j) {                     // redundant per-block reduce (L2-hot)
        int d = j*256 + threadIdx.x;
        float s = 0.f;
        #pragma unroll
        for (int sl = 0; sl < 32; ++sl) s += partial[((size_t)sl*NB + b)*DDIM + d];
        vloc[d] = s;
    }
    __syncthreads();
    int g = threadIdx.x >> 4;
    int t = threadIdx.x & 15;
    int e = blockIdx.x*16 + g;
    const float* w = W + (size_t)e*DDIM;
    float s = 0.f;
    for (int k = t; k < DDIM; k += 16) s += w[k]*vloc[k];
    #pragma unroll
    for (int o = 8; o; o >>= 1) s += __shfl_down(s, o, 16);
    if (t == 0) vout[b*DDIM + e] = s;
}

// ------------------------------------------------------- small matvec: vout = vin @ W^T
__global__ __launch_bounds__(256) void matvec_kernel(
    const float* __restrict__ W, const float* __restrict__ vin, float* __restrict__ vout)
{
    int b = blockIdx.y;
    int g = threadIdx.x >> 4;
    int t = threadIdx.x & 15;
    int e = blockIdx.x*16 + g;
    const float* w = W + (size_t)e*DDIM;
    const float* v = vin + b*DDIM;
    float s = 0.f;
    for (int k = t; k < DDIM; k += 16) s += w[k]*v[k];
    #pragma unroll
    for (int o = 8; o; o >>= 1) s += __shfl_down(s, o, 16);
    if (t == 0) vout[b*DDIM + e] = s;
}

// ------------------------------------------------------- LN1: x1 = LN(x + attnvec) -> bf16
__global__ __launch_bounds__(256) void ln1_kernel(
    const float* __restrict__ x, const float* __restrict__ avec,
    const float* __restrict__ g1, const float* __restrict__ b1,
    unsigned short* __restrict__ x1b)
{
    int row = blockIdx.x;
    int b   = row >> 12;          // row / SEQ
    int tid = threadIdx.x;
    const float4* xr = (const float4*)(x + (size_t)row*DDIM);
    const float4* av = (const float4*)(avec + (size_t)b*DDIM);
    float4 xv = xr[tid], a4 = av[tid];
    float y0 = xv.x+a4.x, y1 = xv.y+a4.y, y2 = xv.z+a4.z, y3 = xv.w+a4.w;
    float s  = y0+y1+y2+y3;
    float ss = y0*y0+y1*y1+y2*y2+y3*y3;
    #pragma unroll
    for (int o = 32; o; o >>= 1) { s += __shfl_down(s,o,64); ss += __shfl_down(ss,o,64); }
    __shared__ float red[8];
    if ((tid&63) == 0) { red[tid>>6] = s; red[4+(tid>>6)] = ss; }
    __syncthreads();
    float St = red[0]+red[1]+red[2]+red[3];
    float Sq = red[4]+red[5]+red[6]+red[7];
    float mu = St*(1.0f/DDIM);
    float rs = rsqrtf(Sq*(1.0f/DDIM) - mu*mu + 1e-5f);
    float4 g4 = ((const float4*)g1)[tid];
    float4 bb = ((const float4*)b1)[tid];
    ushort4 o;
    o.x = f2bf((y0-mu)*rs*g4.x + bb.x);
    o.y = f2bf((y1-mu)*rs*g4.y + bb.y);
    o.z = f2bf((y2-mu)*rs*g4.z + bb.z);
    o.w = f2bf((y3-mu)*rs*g4.w + bb.w);
    *(ushort4*)(x1b + (size_t)row*DDIM + tid*4) = o;
}

// ------------------------------------------------------- GEMM1: round-3 proven config
// 128x128 tile, BK=64, double-buffered 64 KB LDS, counted vmcnt(8), 2 blocks/CU.
// outb = bf16(gelu(A@W1^T + b1))  [tanh-GELU, validated rounds 4-6]
__global__ __launch_bounds__(256, 2) void gemm1_kernel(
    const bf16* __restrict__ A, const bf16* __restrict__ Bw,
    const float* __restrict__ bias, unsigned short* __restrict__ outb)
{
    constexpr int K = 1024, N = 1024, BK = 64, NT = K / BK;   // 16 K-tiles
    __shared__ __align__(16) bf16 lds[2][2][128*BK];          // 64 KB
    const int tid  = threadIdx.x;
    const int wave = tid >> 6, lane = tid & 63;

    int bid = blockIdx.x;
    int swz = (bid & 7) * 128 + (bid >> 3);     // T1 bijective XCD swizzle (grid 1024)
    const size_t bm = (size_t)(swz >> 3) * 128;
    const size_t bn = (size_t)(swz & 7) * 128;

    const int wm = wave >> 1;     // 0..1
    const int wn = wave & 1;      // 0..1

    const int srow = tid >> 3;
    const int skel = (((tid & 7) ^ ((tid >> 3) & 7)) << 3);

    const int fr = lane & 15;
    const int fs = lane >> 4;
    int foff[2];
    #pragma unroll
    for (int ks = 0; ks < 2; ++ks)
        foff[ks] = fr*128 + (((ks*4 + fs) ^ (fr & 7)) << 4);

    f32x4 acc[4][4] = {};
    const bf16* Ab = A  + bm * K;
    const bf16* Bb = Bw + bn * K;

    auto stage = [&](int b, int kt) {        // 8 global_load_lds (16B each)
        #pragma unroll
        for (int mat = 0; mat < 2; ++mat) {
            const bf16* src = (mat == 0 ? Ab : Bb);
            #pragma unroll
            for (int g = 0; g < 4; ++g) {
                int row = g*32 + srow;
                const bf16* gp = src + (size_t)row * K + kt*BK + skel;
                __builtin_amdgcn_global_load_lds(
                    (const __attribute__((address_space(1))) void*)gp,
                    (__attribute__((address_space(3))) void*)
                        ((char*)&lds[b][mat][0] + g*4096 + wave*1024),
                    16, 0, 0);
            }
        }
    };

    stage(0, 0);

    #pragma unroll 2
    for (int t = 0; t < NT; ++t) {
        const int cur = t & 1;
        if (t < NT-1) {
            stage(cur ^ 1, t + 1);
            asm volatile("s_waitcnt vmcnt(8)" ::: "memory");
        } else {
            asm volatile("s_waitcnt vmcnt(0)" ::: "memory");
        }
        __builtin_amdgcn_s_barrier();

        const char* LA = (const char*)&lds[cur][0][0] + wm*8192;
        const char* LB = (const char*)&lds[cur][1][0] + wn*8192;
        #pragma unroll
        for (int ks = 0; ks < 2; ++ks) {
            short8 af[4], bfr[4];
            #pragma unroll
            for (int m = 0; m < 4; ++m) af[m]  = *(const short8*)(LA + m*2048 + foff[ks]);
            #pragma unroll
            for (int n = 0; n < 4; ++n) bfr[n] = *(const short8*)(LB + n*2048 + foff[ks]);
            __builtin_amdgcn_s_setprio(1);
            #pragma unroll
            for (int m = 0; m < 4; ++m)
                #pragma unroll
                for (int n = 0; n < 4; ++n)
                    acc[m][n] = __builtin_amdgcn_mfma_f32_16x16x32_bf16(
                        af[m], bfr[n], acc[m][n], 0, 0, 0);
            __builtin_amdgcn_s_setprio(0);
        }
        __builtin_amdgcn_s_barrier();
    }

    #pragma unroll
    for (int n = 0; n < 4; ++n) {
        size_t col = bn + wn*64 + n*16 + fr;
        float bv = bias[col];
        #pragma unroll
        for (int m = 0; m < 4; ++m) {
            #pragma unroll
            for (int r = 0; r < 4; ++r) {
                size_t row = bm + wm*64 + m*16 + fs*4 + r;
                float v = acc[m][n][r] + bv;
                float u = 0.7978845608f * (v + 0.044715f*v*v*v);
                float e = __expf(2.0f*u);
                float ge = 0.5f*v*(1.0f + (1.0f - 2.0f/(e + 1.0f)));
                outb[row*(size_t)N + col] = f2bf(ge);
            }
        }
    }
}

// ------------------------------------------------------- GEMM2: proven K-loop + fused stats
// y = bf16(A@W2^T + b2 + resid) written IN PLACE over resid (xy); per-block row partial
// sums/sumsq of quantized y -> part[row*8 + bn/128]. LN2 applied in a later pass.
__global__ __launch_bounds__(256, 2) void gemm2_kernel(
    const bf16* __restrict__ A, const bf16* __restrict__ Bw,
    const float* __restrict__ bias, unsigned short* __restrict__ xy,
    float2* __restrict__ part)
{
    constexpr int K = 1024, N = 1024, BK = 64, NT = K / BK;   // 16 K-tiles
    __shared__ __align__(16) bf16 lds[2][2][128*BK];          // 64 KB
    const int tid  = threadIdx.x;
    const int wave = tid >> 6, lane = tid & 63;

    int bid = blockIdx.x;
    int swz = (bid & 7) * 128 + (bid >> 3);
    const size_t bm = (size_t)(swz >> 3) * 128;
    const size_t bn = (size_t)(swz & 7) * 128;

    const int wm = wave >> 1;
    const int wn = wave & 1;

    const int srow = tid >> 3;
    const int skel = (((tid & 7) ^ ((tid >> 3) & 7)) << 3);

    const int fr = lane & 15;
    const int fs = lane >> 4;
    int foff[2];
    #pragma unroll
    for (int ks = 0; ks < 2; ++ks)
        foff[ks] = fr*128 + (((ks*4 + fs) ^ (fr & 7)) << 4);

    f32x4 acc[4][4] = {};
    const bf16* Ab = A  + bm * K;
    const bf16* Bb = Bw + bn * K;

    auto stage = [&](int b, int kt) {
        #pragma unroll
        for (int mat = 0; mat < 2; ++mat) {
            const bf16* src = (mat == 0 ? Ab : Bb);
            #pragma unroll
            for (int g = 0; g < 4; ++g) {
                int row = g*32 + srow;
                const bf16* gp = src + (size_t)row * K + kt*BK + skel;
                __builtin_amdgcn_global_load_lds(
                    (const __attribute__((address_space(1))) void*)gp,
                    (__attribute__((address_space(3))) void*)
                        ((char*)&lds[b][mat][0] + g*4096 + wave*1024),
                    16, 0, 0);
            }
        }
    };

    stage(0, 0);

    #pragma unroll 2
    for (int t = 0; t < NT; ++t) {
        const int cur = t & 1;
        if (t < NT-1) {
            stage(cur ^ 1, t + 1);
            asm volatile("s_waitcnt vmcnt(8)" ::: "memory");
        } else {
            asm volatile("s_waitcnt vmcnt(0)" ::: "memory");
        }
        __builtin_amdgcn_s_barrier();

        const char* LA = (const char*)&lds[cur][0][0] + wm*8192;
        const char* LB = (const char*)&lds[cur][1][0] + wn*8192;
        #pragma unroll
        for (int ks = 0; ks < 2; ++ks) {
            short8 af[4], bfr[4];
            #pragma unroll
            for (int m = 0; m < 4; ++m) af[m]  = *(const short8*)(LA + m*2048 + foff[ks]);
            #pragma unroll
            for (int n = 0; n < 4; ++n) bfr[n] = *(const short8*)(LB + n*2048 + foff[ks]);
            __builtin_amdgcn_s_setprio(1);
            #pragma unroll
            for (int m = 0; m < 4; ++m)
                #pragma unroll
                for (int n = 0; n < 4; ++n)
                    acc[m][n] = __builtin_amdgcn_mfma_f32_16x16x32_bf16(
                        af[m], bfr[n], acc[m][n], 0, 0, 0);
            __builtin_amdgcn_s_setprio(0);
        }
        __builtin_amdgcn_s_barrier();
    }

    // ---- epilogue: quantize y to bf16 in place, accumulate row stats of quantized y
    float vs[4][4] = {}, vq[4][4] = {};
    #pragma unroll
    for (int n = 0; n < 4; ++n) {
        size_t col = bn + wn*64 + n*16 + fr;
        float bv = bias[col];
        #pragma unroll
        for (int m = 0; m < 4; ++m) {
            #pragma unroll
            for (int r = 0; r < 4; ++r) {
                size_t row = bm + wm*64 + m*16 + fs*4 + r;
                size_t idx = row*(size_t)N + col;
                float v = acc[m][n][r] + bv + bf2f(xy[idx]);
                unsigned short qb = f2bf(v);
                xy[idx] = qb;                      // y bf16, in place over resid
                float vv = bf2f(qb);
                vs[m][r] += vv;
                vq[m][r] += vv*vv;
            }
        }
    }
    #pragma unroll
    for (int o = 1; o < 16; o <<= 1) {
        #pragma unroll
        for (int m = 0; m < 4; ++m)
            #pragma unroll
            for (int r = 0; r < 4; ++r) {
                vs[m][r] += __shfl_xor(vs[m][r], o);
                vq[m][r] += __shfl_xor(vq[m][r], o);
            }
    }
    float* lred = (float*)&lds[0][0][0];           // [wn:2][128 rows][2]
    if (fr == 0) {
        #pragma unroll
        for (int m = 0; m < 4; ++m)
            #pragma unroll
            for (int r = 0; r < 4; ++r) {
                int rl = wm*64 + m*16 + fs*4 + r;
                lred[(wn*128 + rl)*2]     = vs[m][r];
                lred[(wn*128 + rl)*2 + 1] = vq[m][r];
            }
    }
    __syncthreads();
    if (tid < 128) {
        float s  = lred[tid*2]       + lred[(128 + tid)*2];
        float sq = lred[tid*2 + 1]   + lred[(128 + tid)*2 + 1];
        part[(bm + tid)*8 + (bn >> 7)] = make_float2(s, sq);
    }
}

// ------------------------------------------------------- LN2 apply: out = LN(y) fp32
__global__ __launch_bounds__(256) void ln2_apply_kernel(
    const unsigned short* __restrict__ yb, const float2* __restrict__ part,
    const float* __restrict__ g2, const float* __restrict__ b2,
    float* __restrict__ out)
{
    int row = blockIdx.x;
    int tid = threadIdx.x;
    float s = 0.f, sq = 0.f;
    #pragma unroll
    for (int i = 0; i < 8; ++i) {                  // row uniform -> broadcast loads
        float2 p = part[(size_t)row*8 + i];
        s += p.x; sq += p.y;
    }
    float mu = s * (1.0f/DDIM);
    float rs = rsqrtf(sq * (1.0f/DDIM) - mu*mu + 1e-5f);
    ushort4 yv = *(const ushort4*)(yb + (size_t)row*DDIM + tid*4);
    float4 g4 = ((const float4*)g2)[tid];
    float4 bb = ((const float4*)b2)[tid];
    float4 o;
    o.x = (bf2f(yv.x) - mu)*rs*g4.x + bb.x;
    o.y = (bf2f(yv.y) - mu)*rs*g4.y + bb.y;
    o.z = (bf2f(yv.z) - mu)*rs*g4.z + bb.z;
    o.w = (bf2f(yv.w) - mu)*rs*g4.w + bb.w;
    ((float4*)(out + (size_t)row*DDIM))[tid] = o;
}

// ---------------------------------------------------------------- launch
extern "C" void kernel_launch(void* const* d_in, const int* in_sizes, int n_in,
                              void* d_out, int out_size, void* d_ws, size_t ws_size,
                              hipStream_t stream)
{
    const float* x     = (const float*)d_in[0];
    const float* w_qkv = (const float*)d_in[1];
    const float* w_o   = (const float*)d_in[2];
    const float* w1    = (const float*)d_in[3];
    const float* b1    = (const float*)d_in[4];
    const float* w2    = (const float*)d_in[5];
    const float* b2    = (const float*)d_in[6];
    const float* ln1g  = (const float*)d_in[7];
    const float* ln1b  = (const float*)d_in[8];
    const float* ln2g  = (const float*)d_in[9];
    const float* ln2b  = (const float*)d_in[10];
    float* out = (float*)d_out;
    char* ws = (char*)d_ws;

    unsigned short* x1b = (unsigned short*)(ws);               // 32 MB  x1 bf16 -> later y bf16
    unsigned short* hb  = (unsigned short*)(ws + 33554432);    // 32 MB  h  bf16
    unsigned short* w1b = (unsigned short*)(ws + 67108864);    // 2 MB   (dead after GEMM1 -> partials)
    unsigned short* w2b = (unsigned short*)(ws + 69206016);    // 2 MB
    float* partial = (float*)(ws + 71303168);                  // 512 KB (colsum)
    float* tvec    = (float*)(ws + 71843840);                  // 16 KB
    float* avec    = (float*)(ws + 71860224);                  // 16 KB
    float2* lnpart = (float2*)(ws + 67108864);                 // 1 MB, aliases w1b (safe: GEMM1 done)

    prep_kernel<<<dim3(1536), 256, 0, stream>>>(w1, w2, w1b, w2b, x, partial);
    matvec1_kernel<<<dim3(64, NB), 256, 0, stream>>>(
        w_qkv + (size_t)2*DDIM*DDIM, partial, tvec);
    matvec_kernel<<<dim3(64, NB), 256, 0, stream>>>(w_o, tvec, avec);
    ln1_kernel<<<dim3(MTOT), 256, 0, stream>>>(x, avec, ln1g, ln1b, x1b);
    gemm1_kernel<<<dim3(1024), 256, 0, stream>>>(
        (const bf16*)x1b, (const bf16*)w1b, b1, hb);
    gemm2_kernel<<<dim3(1024), 256, 0, stream>>>(
        (const bf16*)hb, (const bf16*)w2b, b2, x1b, lnpart);
    ln2_apply_kernel<<<dim3(MTOT), 256, 0, stream>>>(x1b, lnpart, ln2g, ln2b, out);
}